// Round 10
// baseline (205.972 us; speedup 1.0000x reference)
//
#include <hip/hip_runtime.h>
#include <hip/hip_bf16.h>
#include <hip/hip_fp16.h>

typedef __attribute__((ext_vector_type(8))) _Float16 half8;  // 8 fp16 = 16x16x32 A/B frag
typedef __attribute__((ext_vector_type(4))) float f32x4;     // 16x16 C/D frag

#define BLOCK 256      // 4 waves
#define GTILE 16       // edges per wave-tile
#define NBKT  32       // dst buckets; bucket%8 -> XCD slot

// W region: logical [row][boff], 256-B rows, XOR ((row&15)<<4) (verified r4-r9).
__device__ __forceinline__ int swz16(int row, int boff) {
    return (row << 8) + (boff ^ ((row & 15) << 4));
}
// Z region: logical [halfrow][boff], 128-B rows, XOR ((row&7)<<4) (verified r4-r9).
__device__ __forceinline__ int swzH(int row, int boff) {
    return (row << 7) + (boff ^ ((row & 7) << 4));
}

__device__ __forceinline__ int probe_i64(const int* eli) {
    int any = 0;
    #pragma unroll
    for (int i = 0; i < 32; ++i) any |= eli[2 * i + 1];
    return (any == 0) ? 1 : 0;   // int64 LE: odd dwords (hi halves) all 0
}

// ---------------- pass 1: f32 -> fp16 tables + dst-bucket histogram ----------------
__global__ __launch_bounds__(256) void cvt_hist_kernel(
    const float* __restrict__ a, const float* __restrict__ b,
    _Float16* __restrict__ oa, _Float16* __restrict__ ob, int n,  // n = N*128
    const int* __restrict__ eli, int E, float scale, unsigned int* __restrict__ cnt)
{
    __shared__ unsigned int h[NBKT];
    __shared__ int s_i64;
    if (threadIdx.x < NBKT) h[threadIdx.x] = 0;
    if (threadIdx.x == 0) s_i64 = probe_i64(eli);
    __syncthreads();

    const int i = blockIdx.x * blockDim.x + threadIdx.x;
    const int stride = gridDim.x * blockDim.x;
    const float4* a4 = (const float4*)a;
    const float4* b4 = (const float4*)b;
    const int n8 = n >> 3;
    for (int j = i; j < n8; j += stride) {
        float4 x0 = a4[2 * j], x1 = a4[2 * j + 1];
        float4 y0 = b4[2 * j], y1 = b4[2 * j + 1];
        union { _Float16 hh[8]; uint4 u; } pa, pb;
        pa.hh[0]=(_Float16)x0.x; pa.hh[1]=(_Float16)x0.y;
        pa.hh[2]=(_Float16)x0.z; pa.hh[3]=(_Float16)x0.w;
        pa.hh[4]=(_Float16)x1.x; pa.hh[5]=(_Float16)x1.y;
        pa.hh[6]=(_Float16)x1.z; pa.hh[7]=(_Float16)x1.w;
        pb.hh[0]=(_Float16)y0.x; pb.hh[1]=(_Float16)y0.y;
        pb.hh[2]=(_Float16)y0.z; pb.hh[3]=(_Float16)y0.w;
        pb.hh[4]=(_Float16)y1.x; pb.hh[5]=(_Float16)y1.y;
        pb.hh[6]=(_Float16)y1.z; pb.hh[7]=(_Float16)y1.w;
        ((uint4*)oa)[j] = pa.u;
        ((uint4*)ob)[j] = pb.u;
    }
    for (int j = (n8 << 3) + i; j < n; j += stride) {
        oa[j] = (_Float16)a[j];
        ob[j] = (_Float16)b[j];
    }
    const int i64f = s_i64;
    for (int e = i; e < E; e += stride) {
        int c = i64f ? eli[2 * ((size_t)E + e)] : eli[(size_t)E + e];
        int bkt = (int)((float)c * scale);
        if (bkt > NBKT - 1) bkt = NBKT - 1;
        atomicAdd(&h[bkt], 1u);
    }
    __syncthreads();
    if (threadIdx.x < NBKT && h[threadIdx.x])
        atomicAdd(&cnt[threadIdx.x], h[threadIdx.x]);
}

// ---------------- pass 2: exclusive scan ----------------
__global__ void scan_kernel(const unsigned int* __restrict__ cnt,
                            unsigned int* __restrict__ segStart,
                            unsigned int* __restrict__ cursor)
{
    if (threadIdx.x == 0) {
        unsigned int s = 0;
        for (int b = 0; b < NBKT; ++b) { segStart[b] = s; cursor[b] = s; s += cnt[b]; }
        segStart[NBKT] = s;
    }
}

// ---------------- pass 3: counting-sort scatter, packed (r,c,orig_e) ----------------
__global__ __launch_bounds__(256) void scatter_kernel(
    const int* __restrict__ eli, int E, float scale,
    unsigned int* __restrict__ cursor, uint2* __restrict__ sorted)
{
    __shared__ unsigned int lcnt[NBKT];
    __shared__ unsigned int lpos[NBKT];
    __shared__ int s_i64;
    if (threadIdx.x < NBKT) lcnt[threadIdx.x] = 0;
    if (threadIdx.x == 0) s_i64 = probe_i64(eli);
    __syncthreads();
    const int i64f = s_i64;

    const int chunk = (E + gridDim.x - 1) / gridDim.x;
    const int e0 = blockIdx.x * chunk;
    const int e1 = min(E, e0 + chunk);

    for (int e = e0 + threadIdx.x; e < e1; e += blockDim.x) {
        int c = i64f ? eli[2 * ((size_t)E + e)] : eli[(size_t)E + e];
        int bkt = (int)((float)c * scale);
        if (bkt > NBKT - 1) bkt = NBKT - 1;
        atomicAdd(&lcnt[bkt], 1u);
    }
    __syncthreads();
    if (threadIdx.x < NBKT) {
        unsigned int nv = lcnt[threadIdx.x];
        lpos[threadIdx.x] = nv ? atomicAdd(&cursor[threadIdx.x], nv) : 0u;
    }
    __syncthreads();
    for (int e = e0 + threadIdx.x; e < e1; e += blockDim.x) {
        int r, c;
        if (i64f) { r = eli[2 * (size_t)e]; c = eli[2 * ((size_t)E + e)]; }
        else      { r = eli[e];             c = eli[(size_t)E + e]; }
        int bkt = (int)((float)c * scale);
        if (bkt > NBKT - 1) bkt = NBKT - 1;
        unsigned int pos = atomicAdd(&lpos[bkt], 1u);
        // pack: r[0:17) | c[17:34) | e[34:64)   (requires N<=2^17, E<2^30)
        unsigned lo = (unsigned)r | ((unsigned)c << 17);
        unsigned hi = ((unsigned)c >> 15) | ((unsigned)e << 2);
        sorted[pos] = make_uint2(lo, hi);
    }
}

// ---------------- main: bucketed fused edge-MLP (fp16, XCD-affine, dist-2) ----------------
__global__ __launch_bounds__(BLOCK, 3) void mlp_sorted_kernel(
    const _Float16* __restrict__ srcb, const _Float16* __restrict__ dstb,
    const uint2* __restrict__ sorted, const unsigned int* __restrict__ segStart,
    const float* __restrict__ W1, const float* __restrict__ b1,
    const float* __restrict__ W2, const float* __restrict__ b2,
    float* __restrict__ out, int E)
{
    __shared__ __align__(16) char lds[49152];   // [0,32K)=W1^T fp16, [32K,48K)=4x4K Z

    const int tid  = threadIdx.x;
    const int lane = tid & 63;
    const int w    = tid >> 6;
    const int rr   = lane & 15;
    const int kgrp = lane >> 4;
    const int rq8  = lane >> 3;
    const int cl   = lane & 7;

    for (int idx = tid; idx < 128 * 128; idx += BLOCK) {
        int k = idx >> 7, n = idx & 127;
        *(_Float16*)(lds + swz16(n, k * 2)) = (_Float16)W1[idx];
    }
    __syncthreads();   // the ONLY barrier

    char* zb = lds + 32768 + (w << 12);

    float b1s[8], w2s[8];
    #pragma unroll
    for (int cb = 0; cb < 8; ++cb) {
        b1s[cb] = b1[cb * 16 + rr];
        w2s[cb] = W2[cb * 16 + rr];
    }
    const float bias2 = b2[0];

    const int x     = blockIdx.x & 7;        // XCD slot
    const int kb    = blockIdx.x >> 3;
    const int nbs   = gridDim.x >> 3;
    const int wslot = kb * 4 + w;
    const int wstep = nbs * 4;

    const half8* s8 = (const half8*)srcb;
    const half8* d8 = (const half8*)dstb;

    half8 svA[4], dvA[4], svB[4], dvB[4];
    int eoA = 0, eoB = 0;
    int s0 = 0, s1 = 0;

    auto loadT = [&](int t, half8 (&s)[4], half8 (&d)[4], int& eo) {
        int idx = s0 + t * 16 + rr; if (idx >= s1) idx = s1 - 1;
        uint2 pk = sorted[idx];
        int r = (int)(pk.x & 0x1FFFFu);
        int c = (int)(((pk.x >> 17) | (pk.y << 15)) & 0x1FFFFu);
        eo = (int)(pk.y >> 2);
        #pragma unroll
        for (int i = 0; i < 4; ++i) {
            int hr = i * 8 + rq8, e = hr >> 1, hh = hr & 1;
            int rn = __shfl(r, e, 64);
            int cn = __shfl(c, e, 64);
            s[i] = s8[(size_t)rn * 16 + hh * 8 + cl];
            d[i] = d8[(size_t)cn * 16 + hh * 8 + cl];
        }
    };
    auto writeZ = [&](const half8 (&s)[4], const half8 (&d)[4]) {
        #pragma unroll
        for (int i = 0; i < 4; ++i) {
            int hr = i * 8 + rq8;
            half8 pr = s[i] * d[i];              // v_pk_mul_f16
            *(half8*)(zb + swzH(hr, cl * 16)) = pr;
        }
    };
    auto compute = [&](int base, int eoCur) {
        int cnt = s1 - base; if (cnt > 16) cnt = 16;
        f32x4 acc[8];
        #pragma unroll
        for (int cb = 0; cb < 8; ++cb) acc[cb] = (f32x4){0.f, 0.f, 0.f, 0.f};
        __builtin_amdgcn_s_setprio(1);
        #pragma unroll
        for (int kk = 0; kk < 4; ++kk) {
            half8 af = *(const half8*)(zb + swzH(rr * 2 + (kk >> 1),
                                                 (kk & 1) * 64 + kgrp * 16));
            #pragma unroll
            for (int cb = 0; cb < 8; ++cb) {
                half8 bf = *(const half8*)(lds + swz16(cb * 16 + rr,
                                                       kk * 64 + kgrp * 16));
                acc[cb] = __builtin_amdgcn_mfma_f32_16x16x32_f16(af, bf, acc[cb], 0, 0, 0);
            }
        }
        __builtin_amdgcn_s_setprio(0);
        #pragma unroll
        for (int r = 0; r < 4; ++r) {
            float p = 0.f;
            #pragma unroll
            for (int cb = 0; cb < 8; ++cb) {
                float hv = acc[cb][r] + b1s[cb];
                hv = fmaxf(hv, 0.f);
                p = fmaf(hv, w2s[cb], p);
            }
            p += __shfl_xor(p, 1, 64);
            p += __shfl_xor(p, 2, 64);
            p += __shfl_xor(p, 4, 64);
            p += __shfl_xor(p, 8, 64);
            int es = kgrp * 4 + r;                       // edge-in-tile
            int eOrig = __shfl(eoCur, es, 64);
            if (rr == 0 && es < cnt)
                out[eOrig] = p + bias2;                  // plain store: L2 coalesces
        }
    };

    for (int j = 0; j < NBKT / 8; ++j) {
        const int b = x + 8 * j;
        s0 = (int)segStart[b];
        s1 = (int)segStart[b + 1];
        if (s1 <= s0) continue;
        const int nt = (s1 - s0 + 15) >> 4;
        int t = wslot;
        if (t >= nt) continue;

        loadT(t, svA, dvA, eoA);                 // tile t   -> A
        if (t + wstep < nt) loadT(t + wstep, svB, dvB, eoB);   // tile t+w -> B

        while (true) {
            // ---- body A
            asm volatile("" ::: "memory");
            writeZ(svA, dvA);
            int eoCur = eoA;
            int tp = t + 2 * wstep;
            if (tp < nt) loadT(tp, svA, dvA, eoA);   // refill A (hides under MFMA)
            asm volatile("" ::: "memory");
            compute(s0 + t * 16, eoCur);
            t += wstep; if (t >= nt) break;

            // ---- body B
            asm volatile("" ::: "memory");
            writeZ(svB, dvB);
            eoCur = eoB;
            tp = t + 2 * wstep;
            if (tp < nt) loadT(tp, svB, dvB, eoB);
            asm volatile("" ::: "memory");
            compute(s0 + t * 16, eoCur);
            t += wstep; if (t >= nt) break;
        }
    }
}

// ---------------- fallback: unsorted (r8 structure, fp16) ----------------
template<int MODE>
__global__ __launch_bounds__(BLOCK, 3) void edge_mlp_fb(
    const float* __restrict__ srcf, const float* __restrict__ dstf,
    const _Float16* __restrict__ srcb, const _Float16* __restrict__ dstb,
    const int* __restrict__ eli,
    const float* __restrict__ W1, const float* __restrict__ b1,
    const float* __restrict__ W2, const float* __restrict__ b2,
    float* __restrict__ out, int E)
{
    __shared__ __align__(16) char lds[49152];
    const int tid  = threadIdx.x;
    const int lane = tid & 63;
    const int w    = tid >> 6;
    const int rr   = lane & 15;
    const int kgrp = lane >> 4;
    const int rq8  = lane >> 3;
    const int cl   = lane & 7;

    for (int idx = tid; idx < 128 * 128; idx += BLOCK) {
        int k = idx >> 7, n = idx & 127;
        *(_Float16*)(lds + swz16(n, k * 2)) = (_Float16)W1[idx];
    }
    int probe = eli[2 * (lane & 31) + 1];
    unsigned long long bl = __ballot(lane < 32 && probe != 0);
    const int i64f = (bl == 0ull) ? 1 : 0;
    __syncthreads();

    char* zb = lds + 32768 + (w << 12);
    float b1s[8], w2s[8];
    #pragma unroll
    for (int cb = 0; cb < 8; ++cb) {
        b1s[cb] = b1[cb * 16 + rr];
        w2s[cb] = W2[cb * 16 + rr];
    }
    const float bias2 = b2[0];

    const int ngroups = (E + GTILE - 1) / GTILE;
    const int step = gridDim.x * 4;
    int g = blockIdx.x * 4 + w;
    if (g >= ngroups) return;

    auto idxload = [&](int gg) -> int {
        gg = gg < ngroups ? gg : ngroups - 1;
        int e = gg * GTILE + rr; if (e >= E) e = E - 1;
        size_t off = (lane < 32) ? (size_t)e : (size_t)E + (size_t)e;
        return i64f ? eli[2 * off] : eli[off];
    };

    half8 sv[4], dv[4];
    auto loadT = [&](int iv) {
        const half8* s8 = (const half8*)srcb;
        const half8* d8 = (const half8*)dstb;
        #pragma unroll
        for (int i = 0; i < 4; ++i) {
            int hr = i * 8 + rq8, e = hr >> 1, hh = hr & 1;
            int r = __shfl(iv, e, 64);
            int c = __shfl(iv, 32 + e, 64);
            sv[i] = s8[(size_t)r * 16 + hh * 8 + cl];
            dv[i] = d8[(size_t)c * 16 + hh * 8 + cl];
        }
    };
    auto stageF = [&](int iv) {
        const float4* s4 = (const float4*)srcf;
        const float4* d4 = (const float4*)dstf;
        #pragma unroll
        for (int i = 0; i < 4; ++i) {
            int hr = i * 8 + rq8, e = hr >> 1, hh = hr & 1;
            int r = __shfl(iv, e, 64);
            int c = __shfl(iv, 32 + e, 64);
            float4 a0 = s4[(size_t)r * 32 + hh * 16 + cl * 2];
            float4 a1 = s4[(size_t)r * 32 + hh * 16 + cl * 2 + 1];
            float4 c0 = d4[(size_t)c * 32 + hh * 16 + cl * 2];
            float4 c1 = d4[(size_t)c * 32 + hh * 16 + cl * 2 + 1];
            union { _Float16 hf[8]; half8 v; } pr;
            pr.hf[0]=(_Float16)(a0.x*c0.x); pr.hf[1]=(_Float16)(a0.y*c0.y);
            pr.hf[2]=(_Float16)(a0.z*c0.z); pr.hf[3]=(_Float16)(a0.w*c0.w);
            pr.hf[4]=(_Float16)(a1.x*c1.x); pr.hf[5]=(_Float16)(a1.y*c1.y);
            pr.hf[6]=(_Float16)(a1.z*c1.z); pr.hf[7]=(_Float16)(a1.w*c1.w);
            *(half8*)(zb + swzH(hr, cl * 16)) = pr.v;
        }
    };
    auto compute = [&](int gg) {
        f32x4 acc[8];
        #pragma unroll
        for (int cb = 0; cb < 8; ++cb) acc[cb] = (f32x4){0.f, 0.f, 0.f, 0.f};
        __builtin_amdgcn_s_setprio(1);
        #pragma unroll
        for (int kk = 0; kk < 4; ++kk) {
            half8 af = *(const half8*)(zb + swzH(rr * 2 + (kk >> 1),
                                                 (kk & 1) * 64 + kgrp * 16));
            #pragma unroll
            for (int cb = 0; cb < 8; ++cb) {
                half8 bf = *(const half8*)(lds + swz16(cb * 16 + rr,
                                                       kk * 64 + kgrp * 16));
                acc[cb] = __builtin_amdgcn_mfma_f32_16x16x32_f16(af, bf, acc[cb], 0, 0, 0);
            }
        }
        __builtin_amdgcn_s_setprio(0);
        #pragma unroll
        for (int r = 0; r < 4; ++r) {
            float p = 0.f;
            #pragma unroll
            for (int cb = 0; cb < 8; ++cb) {
                float hv = acc[cb][r] + b1s[cb];
                hv = fmaxf(hv, 0.f);
                p = fmaf(hv, w2s[cb], p);
            }
            p += __shfl_xor(p, 1, 64);
            p += __shfl_xor(p, 2, 64);
            p += __shfl_xor(p, 4, 64);
            p += __shfl_xor(p, 8, 64);
            int e = gg * GTILE + kgrp * 4 + r;
            if (rr == 0 && e < E) out[e] = p + bias2;
        }
    };

    if constexpr (MODE == 1) {
        int iv = idxload(g);
        loadT(iv);
        while (true) {
            asm volatile("" ::: "memory");
            #pragma unroll
            for (int i = 0; i < 4; ++i) {
                int hr = i * 8 + rq8;
                half8 pr = sv[i] * dv[i];
                *(half8*)(zb + swzH(hr, cl * 16)) = pr;
            }
            int gn = g + step;
            if (gn < ngroups) { int iv2 = idxload(gn); loadT(iv2); }
            asm volatile("" ::: "memory");
            compute(g);
            if (gn >= ngroups) break;
            g = gn;
        }
    } else {
        for (; g < ngroups; g += step) {
            asm volatile("" ::: "memory");
            int iv = idxload(g);
            stageF(iv);
            asm volatile("" ::: "memory");
            compute(g);
        }
    }
}

extern "C" void kernel_launch(void* const* d_in, const int* in_sizes, int n_in,
                              void* d_out, int out_size, void* d_ws, size_t ws_size,
                              hipStream_t stream) {
    const float* src = (const float*)d_in[0];
    const float* dst = (const float*)d_in[1];
    const int*   eli = (const int*)d_in[2];
    const float* W1  = (const float*)d_in[3];
    const float* b1  = (const float*)d_in[4];
    const float* W2  = (const float*)d_in[5];
    const float* b2  = (const float*)d_in[6];
    float* out = (float*)d_out;

    const int E = in_sizes[2] / 2;
    const int n = in_sizes[0];               // N * 128 floats
    const int N = n / 128;
    const float scale = (float)NBKT / (float)N;

    const size_t NB = (size_t)n * sizeof(_Float16);
    const size_t need_full = 4096 + 2 * NB + (size_t)E * 8;
    const size_t need_tab  = 2 * NB + 4096;
    const bool packable = (N <= 131072) && (E < (1 << 29));

    if (ws_size >= need_full && packable) {
        char* wsb = (char*)d_ws;
        unsigned int* cnt      = (unsigned int*)wsb;          // [32]
        unsigned int* segStart = cnt + 32;                    // [33]
        unsigned int* cursor   = segStart + 40;               // [32]
        _Float16* srcb = (_Float16*)(wsb + 4096);
        _Float16* dstb = srcb + n;
        uint2* sorted  = (uint2*)(wsb + 4096 + 2 * NB);

        hipMemsetAsync(wsb, 0, 4096, stream);
        cvt_hist_kernel<<<dim3(2048), dim3(256), 0, stream>>>(
            src, dst, srcb, dstb, n, eli, E, scale, cnt);
        scan_kernel<<<dim3(1), dim3(64), 0, stream>>>(cnt, segStart, cursor);
        scatter_kernel<<<dim3(256), dim3(256), 0, stream>>>(
            eli, E, scale, cursor, sorted);
        mlp_sorted_kernel<<<dim3(768), dim3(BLOCK), 0, stream>>>(
            srcb, dstb, sorted, segStart, W1, b1, W2, b2, out, E);
    } else if (ws_size >= need_tab) {
        char* wsb = (char*)d_ws;
        unsigned int* cnt = (unsigned int*)(wsb + 2 * NB);
        _Float16* sb = (_Float16*)wsb;
        _Float16* db = sb + n;
        hipMemsetAsync(cnt, 0, 4096, stream);
        cvt_hist_kernel<<<dim3(2048), dim3(256), 0, stream>>>(
            src, dst, sb, db, n, eli, E, scale, cnt);   // hist side-effect unused
        const int ngroups = (E + GTILE - 1) / GTILE;
        int nblocks = (ngroups + 3) / 4;
        int grid = nblocks < 768 ? nblocks : 768;
        edge_mlp_fb<1><<<dim3(grid), dim3(BLOCK), 0, stream>>>(
            src, dst, sb, db, eli, W1, b1, W2, b2, out, E);
    } else {
        const int ngroups = (E + GTILE - 1) / GTILE;
        int nblocks = (ngroups + 3) / 4;
        int grid = nblocks < 768 ? nblocks : 768;
        edge_mlp_fb<0><<<dim3(grid), dim3(BLOCK), 0, stream>>>(
            src, dst, (const _Float16*)nullptr, (const _Float16*)nullptr,
            eli, W1, b1, W2, b2, out, E);
    }
}